// Round 2
// baseline (274.677 us; speedup 1.0000x reference)
//
#include <hip/hip_runtime.h>
#include <hip/hip_bf16.h>
#include <math.h>

typedef __attribute__((ext_vector_type(8))) short bf16x8;
typedef __attribute__((ext_vector_type(4))) short bf16x4;
typedef __attribute__((ext_vector_type(4))) float floatx4;

constexpr int kN  = 4096;
constexpr int kD  = 768;
constexpr int kH  = 12;
constexpr int kHD = 64;
constexpr int k3D = 2304;
// Q pre-scale: (1/sqrt(64)) * log2(e) so softmax runs in exp2 domain with no muls
constexpr float kQScale = 0.18033688011112042f;

static __device__ __forceinline__ short f2b(float f) {
    __hip_bfloat16 h = __float2bfloat16(f);
    return *reinterpret_cast<short*>(&h);
}

static __device__ __forceinline__ float fast_exp2(float x) {
#if __has_builtin(__builtin_amdgcn_exp2f)
    return __builtin_amdgcn_exp2f(x);
#else
    return exp2f(x);
#endif
}

// Async global->LDS DMA, 16B per lane. LDS dst is wave-uniform base + lane*16.
static __device__ __forceinline__ void async_copy16(const void* g, void* l) {
    __builtin_amdgcn_global_load_lds(
        (const __attribute__((address_space(1))) void*)g,
        (__attribute__((address_space(3))) void*)l, 16, 0, 0);
}

// Fused prep: section 0 = x fp32->bf16; section 1 = W_qkv transpose->bf16;
// section 2 = W_out transpose->bf16. One launch instead of three.
constexpr int kBlkX  = 1536;            // (4096*768/8)/256
constexpr int kBlkWq = 72 * 24;         // (2304/32) x (768/32)
constexpr int kBlkWo = 24 * 24;         // (768/32) x (768/32)

__global__ __launch_bounds__(256)
void prep(const float* __restrict__ x, const float* __restrict__ Wq,
          const float* __restrict__ Wo, short* __restrict__ Xb,
          short* __restrict__ WqT, short* __restrict__ WoT)
{
    const int bid = blockIdx.x;
    const int tid = threadIdx.x;
    if (bid < kBlkX) {
        const int i = bid * 256 + tid;
        const float4* s = reinterpret_cast<const float4*>(x + (size_t)i * 8);
        float4 a = s[0], b = s[1];
        bf16x8 v;
        v[0] = f2b(a.x); v[1] = f2b(a.y); v[2] = f2b(a.z); v[3] = f2b(a.w);
        v[4] = f2b(b.x); v[5] = f2b(b.y); v[6] = f2b(b.z); v[7] = f2b(b.w);
        *reinterpret_cast<bf16x8*>(Xb + (size_t)i * 8) = v;
        return;
    }
    // transpose sections: src[R][C] -> dst[C][R]
    const float* src; short* dst; int R, C, bx, by;
    if (bid < kBlkX + kBlkWq) {
        const int local = bid - kBlkX;
        src = Wq; dst = WqT; R = kD; C = k3D; bx = local % 72; by = local / 72;
    } else {
        const int local = bid - kBlkX - kBlkWq;
        src = Wo; dst = WoT; R = kD; C = kD; bx = local % 24; by = local / 24;
    }
    __shared__ float t[32][33];
    const int c0 = bx * 32, r0 = by * 32;
    const int tx = tid & 31, ty = tid >> 5;
    #pragma unroll
    for (int i = ty; i < 32; i += 8)
        t[i][tx] = src[(size_t)(r0 + i) * C + c0 + tx];
    __syncthreads();
    #pragma unroll
    for (int i = ty; i < 32; i += 8)
        dst[(size_t)(c0 + i) * R + r0 + tx] = f2b(t[tx][i]);
}

// C[M x N] = A[M x K] * BT[N x K]^T, bf16 in, fp32 acc. 128x128 tile, BK=32.
// m97 structure: async global->LDS staging (16B), unpadded tiles, XOR swizzle.
// MODE 0: Cout fp32 = C + bias;  MODE 1: scatter bf16 Qh(*kQScale), Kh, Vt[h][d][n]
template<int MODE>
__device__ __forceinline__
void gemm_core(const short* __restrict__ A, const short* __restrict__ BT,
               const float* __restrict__ bias, float* __restrict__ Cout,
               short* __restrict__ Qh, short* __restrict__ Kh, short* __restrict__ Vt,
               int N, int K)
{
    const int bm   = blockIdx.x * 128;
    const int bn   = blockIdx.y * 128;
    const int tid  = threadIdx.x;
    const int wave = tid >> 6;
    const int lane = tid & 63;
    const int l15  = lane & 15;
    const int quad = lane >> 4;
    const int l3   = l15 & 3;

    __shared__ alignas(16) short As[128 * 32];
    __shared__ alignas(16) short Bs[128 * 32];

    floatx4 acc[4][4] = {};
    const int wm = (wave >> 1) * 64;
    const int wn = (wave & 1) * 64;

    // staging: 16 rows per issue (4 lanes/row), 2 issues/wave per buffer
    const int srl = lane >> 2;               // row within issue group (0..15)
    const int scc = (lane & 3) ^ (srl & 3);  // swizzled source chunk

    for (int k0 = 0; k0 < K; k0 += 32) {
        __syncthreads();
        #pragma unroll
        for (int j = 0; j < 2; ++j) {
            const int rs = 32 * wave + 16 * j;     // wave-uniform row start
            async_copy16(&A [(size_t)(bm + rs + srl) * K + k0 + 8 * scc], &As[rs * 32]);
            async_copy16(&BT[(size_t)(bn + rs + srl) * K + k0 + 8 * scc], &Bs[rs * 32]);
        }
        __syncthreads();

        bf16x8 af[4], bfr[4];
        #pragma unroll
        for (int mt = 0; mt < 4; ++mt)
            af[mt] = *reinterpret_cast<const bf16x8*>(&As[(wm + 16 * mt + l15) * 32 + 8 * (quad ^ l3)]);
        #pragma unroll
        for (int nt = 0; nt < 4; ++nt)
            bfr[nt] = *reinterpret_cast<const bf16x8*>(&Bs[(wn + 16 * nt + l15) * 32 + 8 * (quad ^ l3)]);
        #pragma unroll
        for (int mt = 0; mt < 4; ++mt)
            #pragma unroll
            for (int nt = 0; nt < 4; ++nt)
                acc[mt][nt] = __builtin_amdgcn_mfma_f32_16x16x32_bf16(af[mt], bfr[nt], acc[mt][nt], 0, 0, 0);
    }

    #pragma unroll
    for (int mt = 0; mt < 4; ++mt) {
        #pragma unroll
        for (int nt = 0; nt < 4; ++nt) {
            #pragma unroll
            for (int r = 0; r < 4; ++r) {
                const int row = bm + wm + mt * 16 + 4 * quad + r;
                const int col = bn + wn + nt * 16 + l15;
                float v = acc[mt][nt][r];
                if (MODE == 0) {
                    Cout[(size_t)row * N + col] = v + bias[col];
                } else {
                    const int proj   = col / kD;       // blocks never span projections
                    const int within = col - proj * kD;
                    const int h = within >> 6;
                    const int d = within & 63;
                    if (proj == 0)      Qh[((size_t)h * kN + row) * kHD + d] = f2b(v * kQScale);
                    else if (proj == 1) Kh[((size_t)h * kN + row) * kHD + d] = f2b(v);
                    else                Vt[((size_t)h * kHD + d) * kN + row] = f2b(v);
                }
            }
        }
    }
}

__global__ __launch_bounds__(256)
void gemm_qkv(const short* __restrict__ A, const short* __restrict__ BT,
              short* __restrict__ Qh, short* __restrict__ Kh, short* __restrict__ Vt)
{
    gemm_core<1>(A, BT, nullptr, nullptr, Qh, Kh, Vt, k3D, kD);
}

__global__ __launch_bounds__(256)
void gemm_out(const short* __restrict__ A, const short* __restrict__ BT,
              const float* __restrict__ bias, float* __restrict__ Cout)
{
    gemm_core<0>(A, BT, bias, Cout, nullptr, nullptr, nullptr, kD, kD);
}

// Flash attention v3: LDS-traffic-minimized.
// Diagnosis: v1/v2 were LDS-pipe-bound (all 4 waves read IDENTICAL kf/vv
// fragments -> 4x redundant ds_read traffic; 64-row Q blocks re-read K/V
// 64x per head -> 1.5 GB of L2 traffic, ~44us floor).
// v3: QBLK=128, 2x2 wave split: wave (wm,wk) owns 64 Q rows x 64-of-128 KV.
//   - K/V LDS read redundancy 4x -> 2x; K/V global re-reads halved.
//   - P goes through a 4KB/wave LDS scratch stored DIRECTLY in A-frag order
//     (one b128 read per fragment), XOR-swizzled, ~2-way conflicts max.
//   - each wave accumulates partial O over its KV half; one LDS reduction
//     at the end combines wk=0/wk=1 partials (conflict-free layout).
//   - denominator: 4 scalar f32 accumulators + shfl quad-reduce + tiny Dr LDS.
// LDS = Ks 16K + Vs 16K + P 16K + Dr 1K = 49KB -> 3 blocks/CU.
// Grid 32x12 = 384 blocks, XCD-swizzled so each XCD touches <=2 heads (~4MB
// K/V working set ~ L2-resident).
__global__ __launch_bounds__(256, 3)
void attn(const short* __restrict__ Qh, const short* __restrict__ Kh,
          const short* __restrict__ Vt, short* __restrict__ AO)
{
    // XCD-aware remap: flat = by*32+bx; xcd = flat%8 gets 48 consecutive
    // work items -> spans <=2 heads.
    const int flat = blockIdx.y * 32 + blockIdx.x;   // 0..383
    const int W    = (flat & 7) * 48 + (flat >> 3);  // bijective (384 = 8*48)
    const int h    = W >> 5;                         // W / 32
    const int q0   = (W & 31) * 128;

    const int tid  = threadIdx.x;
    const int wave = tid >> 6;
    const int lane = tid & 63;
    const int l15  = lane & 15;
    const int quad = lane >> 4;
    const int l7   = l15 & 7;
    const int wm   = wave >> 1;      // Q-half owner
    const int wk   = wave & 1;       // KV-half owner
    const int swz  = (l15 >> 1) & 3; // P chunk swizzle (2-way banks max)

    // 48KB carved from one buffer so the epilogue can overlay a 32KB fp32
    // reduction region on Ks+Vs.
    __shared__ alignas(16) short smem[24576];
    __shared__ float Dr[2][2][4][16];    // [wm][wk][mt][m_low] denom partials
    short* Ks = smem;                    // [128 kv][64 d]   16KB
    short* Vs = smem + 8192;             // [64 d][128 kv]   16KB
    short* P  = smem + 16384;            // [4 waves][4KB A-frag-order scratch]
    short* Pw = P + wave * 2048;         // shorts

    // Q fragments: B-operand of QK^T. qf[mt][s] = Q[q0+64wm+16mt+l15][32s+8quad..+8)
    bf16x8 qf[4][2];
    {
        const size_t qb = ((size_t)h * kN + q0 + 64 * wm + l15) * kHD;
        #pragma unroll
        for (int mt = 0; mt < 4; ++mt)
            #pragma unroll
            for (int s = 0; s < 2; ++s)
                qf[mt][s] = *reinterpret_cast<const bf16x8*>(
                    &Qh[qb + (size_t)(16 * mt) * kHD + 32 * s + 8 * quad]);
    }

    floatx4 oacc[4][4] = {};    // [mt][dt], rows 16mt+4quad+r, cols 16dt+l15
    float dsum[4] = {};         // denom partial for m = 64wm+16mt+l15

    // staging lane constants
    const int krl = lane >> 3;            // K: row within 8-row issue
    const int kcc = (lane & 7) ^ krl;     // K: swizzled source chunk
    const int vrl = lane >> 4;            // V: row within 4-row issue
    const int vp  = lane & 15;            // V: physical chunk

    const size_t kbase = (size_t)h * kN * kHD;   // Kh [h][n][d]
    const size_t vbase = (size_t)h * kHD * kN;   // Vt [h][d][n]

    constexpr int kNT = kN / 128;
    for (int t = 0; t < kNT; ++t) {
        const int kv0 = t * 128;
        __syncthreads();   // prior tile's K/V reads complete
        #pragma unroll
        for (int j = 0; j < 4; ++j) {
            const int rk = 32 * wave + 8 * j;                    // K rows rk..rk+7
            async_copy16(&Kh[kbase + (size_t)(kv0 + rk + krl) * kHD + 8 * kcc],
                         &Ks[rk * 64]);
            const int rv0 = 16 * wave + 4 * j;                   // V rows rv0..rv0+3
            const int rv  = rv0 + vrl;
            async_copy16(&Vt[vbase + (size_t)rv * kN + kv0 + 8 * (vp ^ (rv & 7))],
                         &Vs[rv0 * 128]);
        }
        __syncthreads();   // staging visible

        #pragma unroll
        for (int ks = 0; ks < 2; ++ks) {
            const int kvb = 64 * wk + 32 * ks;     // wave's 32-kv pass base

            // ---- QK: S^T = K Q^T for 32 kv x 64 m ----
            #pragma unroll
            for (int nt = 0; nt < 2; ++nt) {
                floatx4 sacc[4] = {};
                #pragma unroll
                for (int s = 0; s < 2; ++s) {
                    bf16x8 kf = *reinterpret_cast<const bf16x8*>(
                        &Ks[(kvb + 16 * nt + l15) * 64 + 8 * ((4 * s + quad) ^ l7)]);
                    #pragma unroll
                    for (int mt = 0; mt < 4; ++mt)
                        sacc[mt] = __builtin_amdgcn_mfma_f32_16x16x32_bf16(
                            kf, qf[mt][s], sacc[mt], 0, 0, 0);
                }
                // softmax numerator + denom partial + pack to A-frag-order LDS.
                // lane (quad,l15) holds P[kv=kvb+16nt+4quad+r][m=16mt+l15];
                // writer (nt,quad) targets chunk 2nt+(quad>>1), half quad&1 of
                // the reader's b128 fragment (algebra: 8q'+2w+p == 16nt+4q+2p).
                #pragma unroll
                for (int mt = 0; mt < 4; ++mt) {
                    const float p0 = fast_exp2(sacc[mt][0]);
                    const float p1 = fast_exp2(sacc[mt][1]);
                    const float p2 = fast_exp2(sacc[mt][2]);
                    const float p3 = fast_exp2(sacc[mt][3]);
                    dsum[mt] += (p0 + p1) + (p2 + p3);
                    bf16x4 pk;
                    pk[0] = f2b(p0); pk[1] = f2b(p1); pk[2] = f2b(p2); pk[3] = f2b(p3);
                    *reinterpret_cast<bf16x4*>(
                        &Pw[mt * 512 + l15 * 32 +
                            8 * ((2 * nt + (quad >> 1)) ^ swz) + 4 * (quad & 1)]) = pk;
                }
            }

            // ---- PV: O += P V for this 32-kv pass ----
            bf16x8 vv[4];
            #pragma unroll
            for (int dt = 0; dt < 4; ++dt)
                vv[dt] = *reinterpret_cast<const bf16x8*>(
                    &Vs[(16 * dt + l15) * 128 + 8 * ((8 * wk + 4 * ks + quad) ^ l7)]);
            #pragma unroll
            for (int mt = 0; mt < 4; ++mt) {
                bf16x8 pa = *reinterpret_cast<const bf16x8*>(
                    &Pw[mt * 512 + l15 * 32 + 8 * (quad ^ swz)]);
                #pragma unroll
                for (int dt = 0; dt < 4; ++dt)
                    oacc[mt][dt] = __builtin_amdgcn_mfma_f32_16x16x32_bf16(
                        pa, vv[dt], oacc[mt][dt], 0, 0, 0);
            }
        }
    }

    // ---- denominator: reduce across quads, publish per-wave partial ----
    #pragma unroll
    for (int mt = 0; mt < 4; ++mt) {
        float v = dsum[mt];
        v += __shfl_xor(v, 16);
        v += __shfl_xor(v, 32);
        dsum[mt] = v;
    }
    if (quad == 0) {
        #pragma unroll
        for (int mt = 0; mt < 4; ++mt)
            Dr[wm][wk][mt][l15] = dsum[mt];
    }

    // ---- cross-wave O reduction (wk=1 publishes, wk=0 combines+stores) ----
    __syncthreads();   // main-loop LDS reads done; Ks/Vs reusable
    float* red = reinterpret_cast<float*>(smem);   // 8192 floats = 32KB
    if (wk == 1) {
        #pragma unroll
        for (int mt = 0; mt < 4; ++mt)
            #pragma unroll
            for (int dt = 0; dt < 4; ++dt)
                *reinterpret_cast<floatx4*>(
                    &red[wm * 4096 + (mt * 4 + dt) * 256 + l15 * 16 + quad * 4]) =
                    oacc[mt][dt];
    }
    __syncthreads();
    if (wk == 0) {
        #pragma unroll
        for (int mt = 0; mt < 4; ++mt) {
            #pragma unroll
            for (int dt = 0; dt < 4; ++dt)
                oacc[mt][dt] += *reinterpret_cast<const floatx4*>(
                    &red[wm * 4096 + (mt * 4 + dt) * 256 + l15 * 16 + quad * 4]);
        }
        #pragma unroll
        for (int mt = 0; mt < 4; ++mt) {
            // denom for rows m = 16mt + 4quad + r
            floatx4 d0 = *reinterpret_cast<const floatx4*>(&Dr[wm][0][mt][4 * quad]);
            floatx4 d1 = *reinterpret_cast<const floatx4*>(&Dr[wm][1][mt][4 * quad]);
            float inv[4];
            #pragma unroll
            for (int r = 0; r < 4; ++r) inv[r] = 1.0f / (d0[r] + d1[r]);
            #pragma unroll
            for (int dt = 0; dt < 4; ++dt) {
                #pragma unroll
                for (int r = 0; r < 4; ++r) {
                    const int row = q0 + 64 * wm + 16 * mt + 4 * quad + r;
                    const int col = h * kHD + 16 * dt + l15;
                    AO[(size_t)row * kD + col] = f2b(oacc[mt][dt][r] * inv[r]);
                }
            }
        }
    }
}

extern "C" void kernel_launch(void* const* d_in, const int* in_sizes, int n_in,
                              void* d_out, int out_size, void* d_ws, size_t ws_size,
                              hipStream_t stream)
{
    const float* x     = (const float*)d_in[0];  // (4096, 768) fp32
    const float* W_qkv = (const float*)d_in[1];  // (768, 2304) fp32
    const float* W_out = (const float*)d_in[2];  // (768, 768)  fp32
    const float* b_out = (const float*)d_in[3];  // (768,)      fp32
    float* out = (float*)d_out;                  // (4096, 768) fp32

    const size_t HNHD = (size_t)kH * kN * kHD;   // 3,145,728 shorts per tensor
    short* Qh    = (short*)d_ws;                 // [H][N][64]
    short* Kh    = Qh + HNHD;
    short* Vt    = Kh + HNHD;                    // [H][64][N]
    short* Xb    = Vt + HNHD;                    // x bf16 [N][768]; reused as AO
    short* WqkvT = Xb + (size_t)kN * kD;         // [2304][768]
    short* WoutT = WqkvT + (size_t)k3D * kD;     // [768][768]
    short* AO    = Xb;                           // overlay: Xb dead after QKV gemm
    (void)in_sizes; (void)n_in; (void)out_size; (void)ws_size;

    // 0) fused conversions/transposes (one launch)
    prep<<<dim3(kBlkX + kBlkWq + kBlkWo), dim3(256), 0, stream>>>(
        x, W_qkv, W_out, Xb, WqkvT, WoutT);

    // 1) QKV projection + head scatter (Q pre-scaled, V transposed)
    gemm_qkv<<<dim3(kN / 128, k3D / 128), dim3(256), 0, stream>>>(
        Xb, WqkvT, Qh, Kh, Vt);
    // 2) flash attention (QBLK=128, 2x2 wave split)
    attn<<<dim3(kN / 128, kH), dim3(256), 0, stream>>>(Qh, Kh, Vt, AO);
    // 3) output projection + bias -> fp32
    gemm_out<<<dim3(kN / 128, kD / 128), dim3(256), 0, stream>>>(
        AO, WoutT, b_out, out);
}

// Round 3
// 217.607 us; speedup vs baseline: 1.2623x; 1.2623x over previous
//
#include <hip/hip_runtime.h>
#include <hip/hip_bf16.h>
#include <math.h>

typedef __attribute__((ext_vector_type(8))) short bf16x8;
typedef __attribute__((ext_vector_type(4))) short bf16x4;
typedef __attribute__((ext_vector_type(4))) float floatx4;

constexpr int kN  = 4096;
constexpr int kD  = 768;
constexpr int kH  = 12;
constexpr int kHD = 64;
constexpr int k3D = 2304;
// Q pre-scale: (1/sqrt(64)) * log2(e) so softmax runs in exp2 domain with no muls
constexpr float kQScale = 0.18033688011112042f;

static __device__ __forceinline__ short f2b(float f) {
    __hip_bfloat16 h = __float2bfloat16(f);
    return *reinterpret_cast<short*>(&h);
}

static __device__ __forceinline__ float fast_exp2(float x) {
#if __has_builtin(__builtin_amdgcn_exp2f)
    return __builtin_amdgcn_exp2f(x);
#else
    return exp2f(x);
#endif
}

// Async global->LDS DMA, 16B per lane. LDS dst is wave-uniform base + lane*16.
static __device__ __forceinline__ void async_copy16(const void* g, void* l) {
    __builtin_amdgcn_global_load_lds(
        (const __attribute__((address_space(1))) void*)g,
        (__attribute__((address_space(3))) void*)l, 16, 0, 0);
}

// Fused prep: section 0 = x fp32->bf16; section 1 = W_qkv transpose->bf16;
// section 2 = W_out transpose->bf16. One launch instead of three.
constexpr int kBlkX  = 1536;            // (4096*768/8)/256
constexpr int kBlkWq = 72 * 24;         // (2304/32) x (768/32)
constexpr int kBlkWo = 24 * 24;         // (768/32) x (768/32)

__global__ __launch_bounds__(256)
void prep(const float* __restrict__ x, const float* __restrict__ Wq,
          const float* __restrict__ Wo, short* __restrict__ Xb,
          short* __restrict__ WqT, short* __restrict__ WoT)
{
    const int bid = blockIdx.x;
    const int tid = threadIdx.x;
    if (bid < kBlkX) {
        const int i = bid * 256 + tid;
        const float4* s = reinterpret_cast<const float4*>(x + (size_t)i * 8);
        float4 a = s[0], b = s[1];
        bf16x8 v;
        v[0] = f2b(a.x); v[1] = f2b(a.y); v[2] = f2b(a.z); v[3] = f2b(a.w);
        v[4] = f2b(b.x); v[5] = f2b(b.y); v[6] = f2b(b.z); v[7] = f2b(b.w);
        *reinterpret_cast<bf16x8*>(Xb + (size_t)i * 8) = v;
        return;
    }
    // transpose sections: src[R][C] -> dst[C][R]
    const float* src; short* dst; int R, C, bx, by;
    if (bid < kBlkX + kBlkWq) {
        const int local = bid - kBlkX;
        src = Wq; dst = WqT; R = kD; C = k3D; bx = local % 72; by = local / 72;
    } else {
        const int local = bid - kBlkX - kBlkWq;
        src = Wo; dst = WoT; R = kD; C = kD; bx = local % 24; by = local / 24;
    }
    __shared__ float t[32][33];
    const int c0 = bx * 32, r0 = by * 32;
    const int tx = tid & 31, ty = tid >> 5;
    #pragma unroll
    for (int i = ty; i < 32; i += 8)
        t[i][tx] = src[(size_t)(r0 + i) * C + c0 + tx];
    __syncthreads();
    #pragma unroll
    for (int i = ty; i < 32; i += 8)
        dst[(size_t)(c0 + i) * R + r0 + tx] = f2b(t[tx][i]);
}

// C[M x N] = A[M x K] * BT[N x K]^T, bf16 in, fp32 acc. 128x128 tile, BK=32.
// m97 structure: async global->LDS staging (16B), unpadded tiles, XOR swizzle.
// MODE 0: Cout fp32 = C + bias;  MODE 1: scatter bf16 Qh(*kQScale), Kh, Vt[h][d][n]
template<int MODE>
__device__ __forceinline__
void gemm_core(const short* __restrict__ A, const short* __restrict__ BT,
               const float* __restrict__ bias, float* __restrict__ Cout,
               short* __restrict__ Qh, short* __restrict__ Kh, short* __restrict__ Vt,
               int N, int K)
{
    const int bm   = blockIdx.x * 128;
    const int bn   = blockIdx.y * 128;
    const int tid  = threadIdx.x;
    const int wave = tid >> 6;
    const int lane = tid & 63;
    const int l15  = lane & 15;
    const int quad = lane >> 4;
    const int l3   = l15 & 3;

    __shared__ alignas(16) short As[128 * 32];
    __shared__ alignas(16) short Bs[128 * 32];

    floatx4 acc[4][4] = {};
    const int wm = (wave >> 1) * 64;
    const int wn = (wave & 1) * 64;

    // staging: 16 rows per issue (4 lanes/row), 2 issues/wave per buffer
    const int srl = lane >> 2;               // row within issue group (0..15)
    const int scc = (lane & 3) ^ (srl & 3);  // swizzled source chunk

    for (int k0 = 0; k0 < K; k0 += 32) {
        __syncthreads();
        #pragma unroll
        for (int j = 0; j < 2; ++j) {
            const int rs = 32 * wave + 16 * j;     // wave-uniform row start
            async_copy16(&A [(size_t)(bm + rs + srl) * K + k0 + 8 * scc], &As[rs * 32]);
            async_copy16(&BT[(size_t)(bn + rs + srl) * K + k0 + 8 * scc], &Bs[rs * 32]);
        }
        __syncthreads();

        bf16x8 af[4], bfr[4];
        #pragma unroll
        for (int mt = 0; mt < 4; ++mt)
            af[mt] = *reinterpret_cast<const bf16x8*>(&As[(wm + 16 * mt + l15) * 32 + 8 * (quad ^ l3)]);
        #pragma unroll
        for (int nt = 0; nt < 4; ++nt)
            bfr[nt] = *reinterpret_cast<const bf16x8*>(&Bs[(wn + 16 * nt + l15) * 32 + 8 * (quad ^ l3)]);
        #pragma unroll
        for (int mt = 0; mt < 4; ++mt)
            #pragma unroll
            for (int nt = 0; nt < 4; ++nt)
                acc[mt][nt] = __builtin_amdgcn_mfma_f32_16x16x32_bf16(af[mt], bfr[nt], acc[mt][nt], 0, 0, 0);
    }

    #pragma unroll
    for (int mt = 0; mt < 4; ++mt) {
        #pragma unroll
        for (int nt = 0; nt < 4; ++nt) {
            #pragma unroll
            for (int r = 0; r < 4; ++r) {
                const int row = bm + wm + mt * 16 + 4 * quad + r;
                const int col = bn + wn + nt * 16 + l15;
                float v = acc[mt][nt][r];
                if (MODE == 0) {
                    Cout[(size_t)row * N + col] = v + bias[col];
                } else {
                    const int proj   = col / kD;       // blocks never span projections
                    const int within = col - proj * kD;
                    const int h = within >> 6;
                    const int d = within & 63;
                    if (proj == 0)      Qh[((size_t)h * kN + row) * kHD + d] = f2b(v * kQScale);
                    else if (proj == 1) Kh[((size_t)h * kN + row) * kHD + d] = f2b(v);
                    else                Vt[((size_t)h * kHD + d) * kN + row] = f2b(v);
                }
            }
        }
    }
}

__global__ __launch_bounds__(256)
void gemm_qkv(const short* __restrict__ A, const short* __restrict__ BT,
              short* __restrict__ Qh, short* __restrict__ Kh, short* __restrict__ Vt)
{
    gemm_core<1>(A, BT, nullptr, nullptr, Qh, Kh, Vt, k3D, kD);
}

__global__ __launch_bounds__(256)
void gemm_out(const short* __restrict__ A, const short* __restrict__ BT,
              const float* __restrict__ bias, float* __restrict__ Cout)
{
    gemm_core<0>(A, BT, bias, Cout, nullptr, nullptr, nullptr, kD, kD);
}

// Flash attention v4: v2's proven skeleton (dbuf KV=64, 1 barrier/tile,
// ones-MFMA denominator), widened to 32 Q-rows per wave (mt=2) so the
// shared kf/vv fragment reads amortize over 2x the MFMAs:
//   per wave per tile: 20 ds_read_b128 / 36 MFMA  (v2: 18 / 18).
// v3's lesson: 64 rows/wave spilled (qf 32 + oacc 64 VGPR -> 188MB scratch
// traffic). 32 rows/wave peaks ~110 VGPR -> no spill, no launch_bounds cap.
// Blocks are 2 waves (128 thr), QBLK=64 -> grid stays 768 = 3 blocks/CU
// exactly (v3's 384-block grid left half the CUs idle half the time).
// LDS = Ks 2x8K + Vs 2x8K + P 2x4K = 40KB.
// XCD swizzle: 768 = 8 x 96 -> each XCD works ~1.5 heads (~1.5MB K/V, L2-fit).
__global__ __launch_bounds__(128)
void attn(const short* __restrict__ Qh, const short* __restrict__ Kh,
          const short* __restrict__ Vt, short* __restrict__ AO)
{
    const int flat = blockIdx.y * 64 + blockIdx.x;    // 0..767
    const int W    = (flat & 7) * 96 + (flat >> 3);   // bijective XCD remap
    const int h    = W >> 6;                          // W / 64
    const int q0   = (W & 63) * 64;

    const int tid  = threadIdx.x;
    const int wave = tid >> 6;          // 0..1
    const int lane = tid & 63;
    const int l15  = lane & 15;
    const int quad = lane >> 4;
    const int lx   = l15 & 7;

    __shared__ alignas(16) short Ks[2][64 * 64];  // K tile [kv][d], swizzled
    __shared__ alignas(16) short Vs[2][64 * 64];  // V^T tile [d][kv], swizzled
    __shared__ alignas(16) short Pm[2][32 * 64];  // per-wave P [m][kv], swizzled

    // Q fragments: B-operand of QK^T. qf[mt][s] = Q[q0+32w+16mt+l15][32s+8quad..)
    bf16x8 qf[2][2];
    {
        const size_t qb = ((size_t)h * kN + q0 + 32 * wave + l15) * kHD;
        #pragma unroll
        for (int mt = 0; mt < 2; ++mt)
            #pragma unroll
            for (int s = 0; s < 2; ++s)
                qf[mt][s] = *reinterpret_cast<const bf16x8*>(
                    &Qh[qb + (size_t)(16 * mt) * kHD + 32 * s + 8 * quad]);
    }

    // all-ones B fragment: mfma(pa, ones) sums each P row -> softmax denom;
    // C-layout puts denom[row=16mt+4quad+r] in reg r of every lane.
    bf16x8 onesf;
    #pragma unroll
    for (int i = 0; i < 8; ++i) onesf[i] = (short)0x3F80;

    floatx4 oacc[2][4] = {};   // [mt][dt]: rows 16mt+4quad+r, cols 16dt+l15
    floatx4 dacc[2] = {};      // [mt] denom

    // staging lane constants: each issue = 8 rows x 128B; physical chunk
    // (lane&7) holds logical chunk (lane&7)^(row&7)  (XOR swizzle)
    const int srl = lane >> 3;              // row within 8-row issue
    const int scc = (lane & 7) ^ srl;       // swizzled source chunk

    short* Pw = Pm[wave];                   // this wave's 32 x 64 P rows

    const size_t kbase = (size_t)h * kN * kHD;   // Kh [h][n][d]
    const size_t vbase = (size_t)h * kHD * kN;   // Vt [h][d][n]

    auto stage = [&](int b, int kv0) {
        #pragma unroll
        for (int j = 0; j < 4; ++j) {
            const int r0 = 32 * wave + 8 * j;   // 8 K rows (kv) / 8 V rows (d)
            async_copy16(&Kh[kbase + (size_t)(kv0 + r0 + srl) * kHD + 8 * scc],
                         &Ks[b][r0 * 64]);
            async_copy16(&Vt[vbase + (size_t)(r0 + srl) * kN + kv0 + 8 * scc],
                         &Vs[b][r0 * 64]);
        }
    };

    constexpr int kNT = kN / 64;
    int cur = 0;
    stage(0, 0);

    for (int t = 0; t < kNT; ++t) {
        // barrier drains vmcnt: the loads it waits on were issued a full
        // compute phase ago; also fences buf[cur^1] reuse.
        __syncthreads();
        if (t + 1 < kNT) stage(cur ^ 1, (t + 1) * 64);

        const short* Kc = Ks[cur];
        const short* Vc = Vs[cur];

        // ---- QK: S^T = K Q^T (64 kv x 32 m) ----
        #pragma unroll
        for (int nt = 0; nt < 4; ++nt) {
            bf16x8 kf0 = *reinterpret_cast<const bf16x8*>(
                &Kc[(16 * nt + l15) * 64 + 8 * ((quad) ^ lx)]);
            bf16x8 kf1 = *reinterpret_cast<const bf16x8*>(
                &Kc[(16 * nt + l15) * 64 + 8 * ((4 + quad) ^ lx)]);
            floatx4 sacc[2] = {};
            __builtin_amdgcn_s_setprio(1);
            #pragma unroll
            for (int mt = 0; mt < 2; ++mt) {
                sacc[mt] = __builtin_amdgcn_mfma_f32_16x16x32_bf16(kf0, qf[mt][0], sacc[mt], 0, 0, 0);
                sacc[mt] = __builtin_amdgcn_mfma_f32_16x16x32_bf16(kf1, qf[mt][1], sacc[mt], 0, 0, 0);
            }
            __builtin_amdgcn_s_setprio(0);
            // p = exp2(s^T); lane holds rows kv=16nt+4quad+r, col m=16mt+l15;
            // pack 4 kv-consecutive values -> b64 at chunk c=2nt+(quad>>1).
            #pragma unroll
            for (int mt = 0; mt < 2; ++mt) {
                const float p0 = fast_exp2(sacc[mt][0]);
                const float p1 = fast_exp2(sacc[mt][1]);
                const float p2 = fast_exp2(sacc[mt][2]);
                const float p3 = fast_exp2(sacc[mt][3]);
                bf16x4 pk;
                pk[0] = f2b(p0); pk[1] = f2b(p1); pk[2] = f2b(p2); pk[3] = f2b(p3);
                const int c = 2 * nt + (quad >> 1);
                *reinterpret_cast<bf16x4*>(
                    &Pw[mt * 1024 + l15 * 64 + 8 * (c ^ lx) + 4 * (quad & 1)]) = pk;
            }
        }
        // no barrier: Pw is wave-private; per-wave DS ops complete in order

        // ---- PV: O += P V; denom via ones-MFMA ----
        __builtin_amdgcn_s_setprio(1);
        #pragma unroll
        for (int s = 0; s < 2; ++s) {
            bf16x8 vv[4];
            #pragma unroll
            for (int dt = 0; dt < 4; ++dt)
                vv[dt] = *reinterpret_cast<const bf16x8*>(
                    &Vc[(16 * dt + l15) * 64 + 8 * ((4 * s + quad) ^ lx)]);
            #pragma unroll
            for (int mt = 0; mt < 2; ++mt) {
                bf16x8 pa = *reinterpret_cast<const bf16x8*>(
                    &Pw[mt * 1024 + l15 * 64 + 8 * ((4 * s + quad) ^ lx)]);
                dacc[mt] = __builtin_amdgcn_mfma_f32_16x16x32_bf16(pa, onesf, dacc[mt], 0, 0, 0);
                #pragma unroll
                for (int dt = 0; dt < 4; ++dt)
                    oacc[mt][dt] = __builtin_amdgcn_mfma_f32_16x16x32_bf16(
                        pa, vv[dt], oacc[mt][dt], 0, 0, 0);
            }
        }
        __builtin_amdgcn_s_setprio(0);

        cur ^= 1;
    }

    // dacc[mt][r] = denom for Q-row 16mt+4quad+r (same across l15) -> no shfl
    #pragma unroll
    for (int mt = 0; mt < 2; ++mt) {
        float inv[4];
        #pragma unroll
        for (int r = 0; r < 4; ++r) inv[r] = 1.0f / dacc[mt][r];
        #pragma unroll
        for (int dt = 0; dt < 4; ++dt) {
            #pragma unroll
            for (int r = 0; r < 4; ++r) {
                const int row = q0 + 32 * wave + 16 * mt + 4 * quad + r;
                const int col = h * kHD + 16 * dt + l15;
                AO[(size_t)row * kD + col] = f2b(oacc[mt][dt][r] * inv[r]);
            }
        }
    }
}

extern "C" void kernel_launch(void* const* d_in, const int* in_sizes, int n_in,
                              void* d_out, int out_size, void* d_ws, size_t ws_size,
                              hipStream_t stream)
{
    const float* x     = (const float*)d_in[0];  // (4096, 768) fp32
    const float* W_qkv = (const float*)d_in[1];  // (768, 2304) fp32
    const float* W_out = (const float*)d_in[2];  // (768, 768)  fp32
    const float* b_out = (const float*)d_in[3];  // (768,)      fp32
    float* out = (float*)d_out;                  // (4096, 768) fp32

    const size_t HNHD = (size_t)kH * kN * kHD;   // 3,145,728 shorts per tensor
    short* Qh    = (short*)d_ws;                 // [H][N][64]
    short* Kh    = Qh + HNHD;
    short* Vt    = Kh + HNHD;                    // [H][64][N]
    short* Xb    = Vt + HNHD;                    // x bf16 [N][768]; reused as AO
    short* WqkvT = Xb + (size_t)kN * kD;         // [2304][768]
    short* WoutT = WqkvT + (size_t)k3D * kD;     // [768][768]
    short* AO    = Xb;                           // overlay: Xb dead after QKV gemm
    (void)in_sizes; (void)n_in; (void)out_size; (void)ws_size;

    // 0) fused conversions/transposes (one launch)
    prep<<<dim3(kBlkX + kBlkWq + kBlkWo), dim3(256), 0, stream>>>(
        x, W_qkv, W_out, Xb, WqkvT, WoutT);

    // 1) QKV projection + head scatter (Q pre-scaled, V transposed)
    gemm_qkv<<<dim3(kN / 128, k3D / 128), dim3(256), 0, stream>>>(
        Xb, WqkvT, Qh, Kh, Vt);
    // 2) flash attention (2 waves x 32 rows, dbuf KV=64)
    attn<<<dim3(kN / 64, kH), dim3(128), 0, stream>>>(Qh, Kh, Vt, AO);
    // 3) output projection + bias -> fp32
    gemm_out<<<dim3(kN / 128, kD / 128), dim3(256), 0, stream>>>(
        AO, WoutT, b_out, out);
}

// Round 4
// 212.287 us; speedup vs baseline: 1.2939x; 1.0251x over previous
//
#include <hip/hip_runtime.h>
#include <hip/hip_bf16.h>
#include <math.h>

typedef __attribute__((ext_vector_type(8))) short bf16x8;
typedef __attribute__((ext_vector_type(4))) short bf16x4;
typedef __attribute__((ext_vector_type(4))) float floatx4;
typedef __attribute__((ext_vector_type(4))) unsigned int uint4v;

constexpr int kN  = 4096;
constexpr int kD  = 768;
constexpr int kH  = 12;
constexpr int kHD = 64;
constexpr int k3D = 2304;
// Q pre-scale: (1/sqrt(64)) * log2(e) so softmax runs in exp2 domain with no muls
constexpr float kQScale = 0.18033688011112042f;

static __device__ __forceinline__ short f2b(float f) {
    __hip_bfloat16 h = __float2bfloat16(f);
    return *reinterpret_cast<short*>(&h);
}

static __device__ __forceinline__ float fast_exp2(float x) {
#if __has_builtin(__builtin_amdgcn_exp2f)
    return __builtin_amdgcn_exp2f(x);
#else
    return exp2f(x);
#endif
}

// v_cvt_pk_bf16_f32: pack two f32 -> one dword of 2 bf16 (lo, hi)
static __device__ __forceinline__ unsigned cvt_pk_bf16(float lo, float hi) {
    unsigned r;
    asm("v_cvt_pk_bf16_f32 %0, %1, %2" : "=v"(r) : "v"(lo), "v"(hi));
    return r;
}
// permlane swaps (gfx950): both operands read-modify-write.
// swap32: a' = [a0 a1 b0 b1], b' = [a2 a3 b2 b3]   (rows = 16-lane groups)
static __device__ __forceinline__ void permlane32_swap(unsigned &a, unsigned &b) {
    asm("v_permlane32_swap_b32 %0, %1" : "+v"(a), "+v"(b));
}
// swap16: a' = [a0 b0 a2 b2], b' = [a1 b1 a3 b3]
static __device__ __forceinline__ void permlane16_swap(unsigned &a, unsigned &b) {
    asm("v_permlane16_swap_b32 %0, %1" : "+v"(a), "+v"(b));
}

// Async global->LDS DMA, 16B per lane. LDS dst is wave-uniform base + lane*16.
static __device__ __forceinline__ void async_copy16(const void* g, void* l) {
    __builtin_amdgcn_global_load_lds(
        (const __attribute__((address_space(1))) void*)g,
        (__attribute__((address_space(3))) void*)l, 16, 0, 0);
}

// Fused prep: section 0 = x fp32->bf16; section 1 = W_qkv transpose->bf16;
// section 2 = W_out transpose->bf16. One launch instead of three.
constexpr int kBlkX  = 1536;            // (4096*768/8)/256
constexpr int kBlkWq = 72 * 24;         // (2304/32) x (768/32)
constexpr int kBlkWo = 24 * 24;         // (768/32) x (768/32)

__global__ __launch_bounds__(256)
void prep(const float* __restrict__ x, const float* __restrict__ Wq,
          const float* __restrict__ Wo, short* __restrict__ Xb,
          short* __restrict__ WqT, short* __restrict__ WoT)
{
    const int bid = blockIdx.x;
    const int tid = threadIdx.x;
    if (bid < kBlkX) {
        const int i = bid * 256 + tid;
        const float4* s = reinterpret_cast<const float4*>(x + (size_t)i * 8);
        float4 a = s[0], b = s[1];
        bf16x8 v;
        v[0] = f2b(a.x); v[1] = f2b(a.y); v[2] = f2b(a.z); v[3] = f2b(a.w);
        v[4] = f2b(b.x); v[5] = f2b(b.y); v[6] = f2b(b.z); v[7] = f2b(b.w);
        *reinterpret_cast<bf16x8*>(Xb + (size_t)i * 8) = v;
        return;
    }
    // transpose sections: src[R][C] -> dst[C][R]
    const float* src; short* dst; int R, C, bx, by;
    if (bid < kBlkX + kBlkWq) {
        const int local = bid - kBlkX;
        src = Wq; dst = WqT; R = kD; C = k3D; bx = local % 72; by = local / 72;
    } else {
        const int local = bid - kBlkX - kBlkWq;
        src = Wo; dst = WoT; R = kD; C = kD; bx = local % 24; by = local / 24;
    }
    __shared__ float t[32][33];
    const int c0 = bx * 32, r0 = by * 32;
    const int tx = tid & 31, ty = tid >> 5;
    #pragma unroll
    for (int i = ty; i < 32; i += 8)
        t[i][tx] = src[(size_t)(r0 + i) * C + c0 + tx];
    __syncthreads();
    #pragma unroll
    for (int i = ty; i < 32; i += 8)
        dst[(size_t)(c0 + i) * R + r0 + tx] = f2b(t[tx][i]);
}

// C[M x N] = A[M x K] * BT[N x K]^T, bf16 in, fp32 acc. 128x128 tile, BK=32.
// m97 structure: async global->LDS staging (16B), unpadded tiles, XOR swizzle.
// MODE 0: Cout fp32 = C + bias;  MODE 1: scatter bf16 Qh(*kQScale), Kh, Vt[h][d][n]
template<int MODE>
__device__ __forceinline__
void gemm_core(const short* __restrict__ A, const short* __restrict__ BT,
               const float* __restrict__ bias, float* __restrict__ Cout,
               short* __restrict__ Qh, short* __restrict__ Kh, short* __restrict__ Vt,
               int N, int K)
{
    const int bm   = blockIdx.x * 128;
    const int bn   = blockIdx.y * 128;
    const int tid  = threadIdx.x;
    const int wave = tid >> 6;
    const int lane = tid & 63;
    const int l15  = lane & 15;
    const int quad = lane >> 4;
    const int l3   = l15 & 3;

    __shared__ alignas(16) short As[128 * 32];
    __shared__ alignas(16) short Bs[128 * 32];

    floatx4 acc[4][4] = {};
    const int wm = (wave >> 1) * 64;
    const int wn = (wave & 1) * 64;

    // staging: 16 rows per issue (4 lanes/row), 2 issues/wave per buffer
    const int srl = lane >> 2;               // row within issue group (0..15)
    const int scc = (lane & 3) ^ (srl & 3);  // swizzled source chunk

    for (int k0 = 0; k0 < K; k0 += 32) {
        __syncthreads();
        #pragma unroll
        for (int j = 0; j < 2; ++j) {
            const int rs = 32 * wave + 16 * j;     // wave-uniform row start
            async_copy16(&A [(size_t)(bm + rs + srl) * K + k0 + 8 * scc], &As[rs * 32]);
            async_copy16(&BT[(size_t)(bn + rs + srl) * K + k0 + 8 * scc], &Bs[rs * 32]);
        }
        __syncthreads();

        bf16x8 af[4], bfr[4];
        #pragma unroll
        for (int mt = 0; mt < 4; ++mt)
            af[mt] = *reinterpret_cast<const bf16x8*>(&As[(wm + 16 * mt + l15) * 32 + 8 * (quad ^ l3)]);
        #pragma unroll
        for (int nt = 0; nt < 4; ++nt)
            bfr[nt] = *reinterpret_cast<const bf16x8*>(&Bs[(wn + 16 * nt + l15) * 32 + 8 * (quad ^ l3)]);
        #pragma unroll
        for (int mt = 0; mt < 4; ++mt)
            #pragma unroll
            for (int nt = 0; nt < 4; ++nt)
                acc[mt][nt] = __builtin_amdgcn_mfma_f32_16x16x32_bf16(af[mt], bfr[nt], acc[mt][nt], 0, 0, 0);
    }

    #pragma unroll
    for (int mt = 0; mt < 4; ++mt) {
        #pragma unroll
        for (int nt = 0; nt < 4; ++nt) {
            #pragma unroll
            for (int r = 0; r < 4; ++r) {
                const int row = bm + wm + mt * 16 + 4 * quad + r;
                const int col = bn + wn + nt * 16 + l15;
                float v = acc[mt][nt][r];
                if (MODE == 0) {
                    Cout[(size_t)row * N + col] = v + bias[col];
                } else {
                    const int proj   = col / kD;       // blocks never span projections
                    const int within = col - proj * kD;
                    const int h = within >> 6;
                    const int d = within & 63;
                    if (proj == 0)      Qh[((size_t)h * kN + row) * kHD + d] = f2b(v * kQScale);
                    else if (proj == 1) Kh[((size_t)h * kN + row) * kHD + d] = f2b(v);
                    else                Vt[((size_t)h * kHD + d) * kN + row] = f2b(v);
                }
            }
        }
    }
}

__global__ __launch_bounds__(256)
void gemm_qkv(const short* __restrict__ A, const short* __restrict__ BT,
              short* __restrict__ Qh, short* __restrict__ Kh, short* __restrict__ Vt)
{
    gemm_core<1>(A, BT, nullptr, nullptr, Qh, Kh, Vt, k3D, kD);
}

__global__ __launch_bounds__(256)
void gemm_out(const short* __restrict__ A, const short* __restrict__ BT,
              const float* __restrict__ bias, float* __restrict__ Cout)
{
    gemm_core<0>(A, BT, bias, Cout, nullptr, nullptr, nullptr, kD, kD);
}

// Flash attention v5: in-register P + 2x2 wave split at QBLK=64.
// Lessons: v2 (92us) was multi-pipe bound with LDS reads heaviest (all waves
// read identical kf/vv -> 72 b128/block/tile); v4 halved traffic but also
// halved occupancy (6 waves/CU) -> worse. v5 keeps v2's shape (768 blocks of
// 4 waves = 3 blocks/CU, 12 waves/CU) AND cuts LDS reads to 32 b128/block/tile:
//   - wave (wm,wk) owns Q rows [32wm,32wm+32) x kv half [32wk,32wk+32):
//     kf 4 + vv 4 b128 per 18 MFMA.
//   - P never goes to LDS: after swapped QK^T, cvt_pk packs P to bf16 words
//     and v_permlane32_swap+v_permlane16_swap redistribute across quads into
//     exact A-fragment order (derivation: pa.word0 = [X0 X2 Y0 Y2] over quads
//     = swap16(swap32(X,Y)); words 1-3 analogous). 8 cvt_pk + 8 permlane
//     per wave/tile replace 8 ds_writes + 4 ds_reads + scalar f2b packing.
//   - denominator on the MFMA pipe (ones-fragment), partials summed across
//     wk in the epilogue; O partials combined via 16KB LDS overlay on Ks/Vs.
// LDS = Ks 2x8K + Vs 2x8K = 32KB (+256B Dr). No min-occupancy bound (v3's
// spill lesson); expected ~120 VGPR -> 3 waves/SIMD fine.
__global__ __launch_bounds__(256)
void attn(const short* __restrict__ Qh, const short* __restrict__ Kh,
          const short* __restrict__ Vt, short* __restrict__ AO)
{
    const int flat = blockIdx.y * 64 + blockIdx.x;    // 0..767
    const int W    = (flat & 7) * 96 + (flat >> 3);   // bijective XCD remap
    const int h    = W >> 6;                          // W / 64
    const int q0   = (W & 63) * 64;

    const int tid  = threadIdx.x;
    const int wave = tid >> 6;          // 0..3
    const int lane = tid & 63;
    const int l15  = lane & 15;
    const int quad = lane >> 4;
    const int lx   = l15 & 7;
    const int wm   = wave >> 1;         // Q-row half owner
    const int wk   = wave & 1;          // KV half owner

    __shared__ alignas(16) short smem[16384];   // Ks[2]:0..8191, Vs[2]:8192..16383
    __shared__ float Dr[2][2][16];              // [wm][mt][4*quad+r] denom partials
    short* Ks0 = smem;
    short* Vs0 = smem + 8192;

    // Q fragments: B-operand of QK^T. qf[mt][s] = Q[q0+32wm+16mt+l15][32s+8quad..)
    bf16x8 qf[2][2];
    {
        const size_t qb = ((size_t)h * kN + q0 + 32 * wm + l15) * kHD;
        #pragma unroll
        for (int mt = 0; mt < 2; ++mt)
            #pragma unroll
            for (int s = 0; s < 2; ++s)
                qf[mt][s] = *reinterpret_cast<const bf16x8*>(
                    &Qh[qb + (size_t)(16 * mt) * kHD + 32 * s + 8 * quad]);
    }

    // all-ones B fragment: mfma(pa, ones) sums each P row -> softmax denom;
    // C-layout puts denom[row=16mt+4quad+r] in reg r of every lane.
    bf16x8 onesf;
    #pragma unroll
    for (int i = 0; i < 8; ++i) onesf[i] = (short)0x3F80;

    floatx4 oacc[2][4] = {};   // [mt][dt]: rows 32wm+16mt+4quad+r, cols 16dt+l15
    floatx4 dacc[2] = {};      // [mt] denom partial (this wave's kv half)

    // staging lane constants: each issue = 8 rows x 128B; physical chunk
    // (lane&7) holds logical chunk (lane&7)^(row&7)  (XOR swizzle)
    const int srl = lane >> 3;              // row within 8-row issue
    const int scc = (lane & 7) ^ srl;       // swizzled source chunk

    const size_t kbase = (size_t)h * kN * kHD;   // Kh [h][n][d]
    const size_t vbase = (size_t)h * kHD * kN;   // Vt [h][d][n]

    auto stage = [&](int b, int kv0) {
        #pragma unroll
        for (int j = 0; j < 2; ++j) {
            const int r0 = 16 * wave + 8 * j;   // 8 K rows (kv) / 8 V rows (d)
            async_copy16(&Kh[kbase + (size_t)(kv0 + r0 + srl) * kHD + 8 * scc],
                         Ks0 + b * 4096 + r0 * 64);
            async_copy16(&Vt[vbase + (size_t)(r0 + srl) * kN + kv0 + 8 * scc],
                         Vs0 + b * 4096 + r0 * 64);
        }
    };

    constexpr int kNT = kN / 64;
    int cur = 0;
    stage(0, 0);

    for (int t = 0; t < kNT; ++t) {
        // barrier drains vmcnt: the loads it waits on were issued a full
        // compute phase ago; also fences buf[cur^1] reuse.
        __syncthreads();
        if (t + 1 < kNT) stage(cur ^ 1, (t + 1) * 64);

        const short* Kc = Ks0 + cur * 4096;
        const short* Vc = Vs0 + cur * 4096;

        // ---- QK: S^T = K Q^T (this wave: 32 kv x 32 m) ----
        floatx4 sacc[2][2] = {};   // [mt][nt]
        __builtin_amdgcn_s_setprio(1);
        #pragma unroll
        for (int nt = 0; nt < 2; ++nt) {
            #pragma unroll
            for (int s = 0; s < 2; ++s) {
                bf16x8 kf = *reinterpret_cast<const bf16x8*>(
                    &Kc[(32 * wk + 16 * nt + l15) * 64 + 8 * ((4 * s + quad) ^ lx)]);
                #pragma unroll
                for (int mt = 0; mt < 2; ++mt)
                    sacc[mt][nt] = __builtin_amdgcn_mfma_f32_16x16x32_bf16(
                        kf, qf[mt][s], sacc[mt][nt], 0, 0, 0);
            }
        }
        __builtin_amdgcn_s_setprio(0);

        // ---- softmax numerator -> in-register A-fragments via permlane ----
        // producer: lane(l15,q') holds P[m][kv=16nt+4q'+r]; consumer A-frag
        // needs lane(l15,Q) to hold kv=8Q+p, p=0..7 packed as 4 dwords.
        // word0(p01)=[X0 X2 Y0 Y2], word2(p45)=[X1 X3 Y1 Y3] over quads where
        // X=pk(nt0;r01), Y=pk(nt1;r01): exactly swap16(swap32(X,Y)).
        bf16x8 pa[2];
        #pragma unroll
        for (int mt = 0; mt < 2; ++mt) {
            float e[2][4];
            #pragma unroll
            for (int nt = 0; nt < 2; ++nt)
                #pragma unroll
                for (int r = 0; r < 4; ++r)
                    e[nt][r] = fast_exp2(sacc[mt][nt][r]);
            unsigned x0 = cvt_pk_bf16(e[0][0], e[0][1]);   // X (r0,r1)
            unsigned y0 = cvt_pk_bf16(e[1][0], e[1][1]);   // Y (r0,r1)
            unsigned x1 = cvt_pk_bf16(e[0][2], e[0][3]);   // X (r2,r3)
            unsigned y1 = cvt_pk_bf16(e[1][2], e[1][3]);   // Y (r2,r3)
            permlane32_swap(x0, y0);   // x0=[X0 X1 Y0 Y1], y0=[X2 X3 Y2 Y3]
            permlane16_swap(x0, y0);   // x0=[X0 X2 Y0 Y2]=w0, y0=[X1 X3 Y1 Y3]=w2
            permlane32_swap(x1, y1);
            permlane16_swap(x1, y1);   // x1=w1, y1=w3
            union { uint4v u; bf16x8 v; } pu;
            pu.u[0] = x0; pu.u[1] = x1; pu.u[2] = y0; pu.u[3] = y1;
            pa[mt] = pu.v;
        }

        // ---- PV: O += P V over this wave's 32 kv; denom via ones-MFMA ----
        __builtin_amdgcn_s_setprio(1);
        #pragma unroll
        for (int dt = 0; dt < 4; ++dt) {
            bf16x8 vv = *reinterpret_cast<const bf16x8*>(
                &Vc[(16 * dt + l15) * 64 + 8 * ((4 * wk + quad) ^ lx)]);
            #pragma unroll
            for (int mt = 0; mt < 2; ++mt)
                oacc[mt][dt] = __builtin_amdgcn_mfma_f32_16x16x32_bf16(
                    pa[mt], vv, oacc[mt][dt], 0, 0, 0);
        }
        #pragma unroll
        for (int mt = 0; mt < 2; ++mt)
            dacc[mt] = __builtin_amdgcn_mfma_f32_16x16x32_bf16(
                pa[mt], onesf, dacc[mt], 0, 0, 0);
        __builtin_amdgcn_s_setprio(0);

        cur ^= 1;
    }

    // ---- epilogue: combine wk=0/1 partials (O and denom) ----
    __syncthreads();   // all main-loop LDS reads done; smem reusable
    float* red = reinterpret_cast<float*>(smem);   // 4096 floats = 16KB
    if (wk == 1) {
        #pragma unroll
        for (int mt = 0; mt < 2; ++mt)
            #pragma unroll
            for (int dt = 0; dt < 4; ++dt)
                *reinterpret_cast<floatx4*>(
                    &red[wm * 2048 + (mt * 4 + dt) * 256 + l15 * 16 + quad * 4]) =
                    oacc[mt][dt];
        if (l15 == 0) {
            #pragma unroll
            for (int mt = 0; mt < 2; ++mt)
                #pragma unroll
                for (int r = 0; r < 4; ++r)
                    Dr[wm][mt][4 * quad + r] = dacc[mt][r];
        }
    }
    __syncthreads();
    if (wk == 0) {
        #pragma unroll
        for (int mt = 0; mt < 2; ++mt) {
            #pragma unroll
            for (int dt = 0; dt < 4; ++dt)
                oacc[mt][dt] += *reinterpret_cast<const floatx4*>(
                    &red[wm * 2048 + (mt * 4 + dt) * 256 + l15 * 16 + quad * 4]);
            float inv[4];
            #pragma unroll
            for (int r = 0; r < 4; ++r)
                inv[r] = 1.0f / (dacc[mt][r] + Dr[wm][mt][4 * quad + r]);
            #pragma unroll
            for (int dt = 0; dt < 4; ++dt) {
                #pragma unroll
                for (int r = 0; r < 4; ++r) {
                    const int row = q0 + 32 * wm + 16 * mt + 4 * quad + r;
                    const int col = h * kHD + 16 * dt + l15;
                    AO[(size_t)row * kD + col] = f2b(oacc[mt][dt][r] * inv[r]);
                }
            }
        }
    }
}

extern "C" void kernel_launch(void* const* d_in, const int* in_sizes, int n_in,
                              void* d_out, int out_size, void* d_ws, size_t ws_size,
                              hipStream_t stream)
{
    const float* x     = (const float*)d_in[0];  // (4096, 768) fp32
    const float* W_qkv = (const float*)d_in[1];  // (768, 2304) fp32
    const float* W_out = (const float*)d_in[2];  // (768, 768)  fp32
    const float* b_out = (const float*)d_in[3];  // (768,)      fp32
    float* out = (float*)d_out;                  // (4096, 768) fp32

    const size_t HNHD = (size_t)kH * kN * kHD;   // 3,145,728 shorts per tensor
    short* Qh    = (short*)d_ws;                 // [H][N][64]
    short* Kh    = Qh + HNHD;
    short* Vt    = Kh + HNHD;                    // [H][64][N]
    short* Xb    = Vt + HNHD;                    // x bf16 [N][768]; reused as AO
    short* WqkvT = Xb + (size_t)kN * kD;         // [2304][768]
    short* WoutT = WqkvT + (size_t)k3D * kD;     // [768][768]
    short* AO    = Xb;                           // overlay: Xb dead after QKV gemm
    (void)in_sizes; (void)n_in; (void)out_size; (void)ws_size;

    // 0) fused conversions/transposes (one launch)
    prep<<<dim3(kBlkX + kBlkWq + kBlkWo), dim3(256), 0, stream>>>(
        x, W_qkv, W_out, Xb, WqkvT, WoutT);

    // 1) QKV projection + head scatter (Q pre-scaled, V transposed)
    gemm_qkv<<<dim3(kN / 128, k3D / 128), dim3(256), 0, stream>>>(
        Xb, WqkvT, Qh, Kh, Vt);
    // 2) flash attention (4 waves: 2 Q-halves x 2 KV-halves, in-register P)
    attn<<<dim3(kN / 64, kH), dim3(256), 0, stream>>>(Qh, Kh, Vt, AO);
    // 3) output projection + bias -> fp32
    gemm_out<<<dim3(kN / 128, kD / 128), dim3(256), 0, stream>>>(
        AO, WoutT, b_out, out);
}

// Round 5
// 196.999 us; speedup vs baseline: 1.3943x; 1.0776x over previous
//
#include <hip/hip_runtime.h>
#include <hip/hip_bf16.h>
#include <math.h>

typedef __attribute__((ext_vector_type(8))) short bf16x8;
typedef __attribute__((ext_vector_type(4))) short bf16x4;
typedef __attribute__((ext_vector_type(4))) float floatx4;
typedef __attribute__((ext_vector_type(4))) unsigned int uint4v;

constexpr int kN  = 4096;
constexpr int kD  = 768;
constexpr int kH  = 12;
constexpr int kHD = 64;
constexpr int k3D = 2304;
// Q pre-scale: (1/sqrt(64)) * log2(e) so softmax runs in exp2 domain with no muls
constexpr float kQScale = 0.18033688011112042f;

static __device__ __forceinline__ short f2b(float f) {
    __hip_bfloat16 h = __float2bfloat16(f);
    return *reinterpret_cast<short*>(&h);
}

static __device__ __forceinline__ float fast_exp2(float x) {
#if __has_builtin(__builtin_amdgcn_exp2f)
    return __builtin_amdgcn_exp2f(x);
#else
    return exp2f(x);
#endif
}

// v_cvt_pk_bf16_f32: pack two f32 -> one dword of 2 bf16 (lo, hi)
static __device__ __forceinline__ unsigned cvt_pk_bf16(float lo, float hi) {
    unsigned r;
    asm("v_cvt_pk_bf16_f32 %0, %1, %2" : "=v"(r) : "v"(lo), "v"(hi));
    return r;
}
// permlane swaps (gfx950): both operands read-modify-write.
static __device__ __forceinline__ void permlane32_swap(unsigned &a, unsigned &b) {
    asm("v_permlane32_swap_b32 %0, %1" : "+v"(a), "+v"(b));
}
static __device__ __forceinline__ void permlane16_swap(unsigned &a, unsigned &b) {
    asm("v_permlane16_swap_b32 %0, %1" : "+v"(a), "+v"(b));
}

// Async global->LDS DMA, 16B per lane. LDS dst is wave-uniform base + lane*16.
static __device__ __forceinline__ void async_copy16(const void* g, void* l) {
    __builtin_amdgcn_global_load_lds(
        (const __attribute__((address_space(1))) void*)g,
        (__attribute__((address_space(3))) void*)l, 16, 0, 0);
}

// Fused prep: section 0 = x fp32->bf16; section 1 = W_qkv transpose->bf16;
// section 2 = W_out transpose->bf16. One launch instead of three.
constexpr int kBlkX  = 1536;            // (4096*768/8)/256
constexpr int kBlkWq = 72 * 24;         // (2304/32) x (768/32)
constexpr int kBlkWo = 24 * 24;         // (768/32) x (768/32)

__global__ __launch_bounds__(256)
void prep(const float* __restrict__ x, const float* __restrict__ Wq,
          const float* __restrict__ Wo, short* __restrict__ Xb,
          short* __restrict__ WqT, short* __restrict__ WoT)
{
    const int bid = blockIdx.x;
    const int tid = threadIdx.x;
    if (bid < kBlkX) {
        const int i = bid * 256 + tid;
        const float4* s = reinterpret_cast<const float4*>(x + (size_t)i * 8);
        float4 a = s[0], b = s[1];
        bf16x8 v;
        v[0] = f2b(a.x); v[1] = f2b(a.y); v[2] = f2b(a.z); v[3] = f2b(a.w);
        v[4] = f2b(b.x); v[5] = f2b(b.y); v[6] = f2b(b.z); v[7] = f2b(b.w);
        *reinterpret_cast<bf16x8*>(Xb + (size_t)i * 8) = v;
        return;
    }
    // transpose sections: src[R][C] -> dst[C][R]
    const float* src; short* dst; int R, C, bx, by;
    if (bid < kBlkX + kBlkWq) {
        const int local = bid - kBlkX;
        src = Wq; dst = WqT; R = kD; C = k3D; bx = local % 72; by = local / 72;
    } else {
        const int local = bid - kBlkX - kBlkWq;
        src = Wo; dst = WoT; R = kD; C = kD; bx = local % 24; by = local / 24;
    }
    __shared__ float t[32][33];
    const int c0 = bx * 32, r0 = by * 32;
    const int tx = tid & 31, ty = tid >> 5;
    #pragma unroll
    for (int i = ty; i < 32; i += 8)
        t[i][tx] = src[(size_t)(r0 + i) * C + c0 + tx];
    __syncthreads();
    #pragma unroll
    for (int i = ty; i < 32; i += 8)
        dst[(size_t)(c0 + i) * R + r0 + tx] = f2b(t[tx][i]);
}

// C[M x N] = A[M x K] * BT[N x K]^T, bf16 in, fp32 acc. 128x128 tile, BK=32.
// m97 structure: async global->LDS staging (16B), unpadded tiles, XOR swizzle.
// MODE 0: Cout fp32 = C + bias;  MODE 1: scatter bf16 Qh(*kQScale), Kh, Vt[h][d][n]
template<int MODE>
__device__ __forceinline__
void gemm_core(const short* __restrict__ A, const short* __restrict__ BT,
               const float* __restrict__ bias, float* __restrict__ Cout,
               short* __restrict__ Qh, short* __restrict__ Kh, short* __restrict__ Vt,
               int N, int K)
{
    const int bm   = blockIdx.x * 128;
    const int bn   = blockIdx.y * 128;
    const int tid  = threadIdx.x;
    const int wave = tid >> 6;
    const int lane = tid & 63;
    const int l15  = lane & 15;
    const int quad = lane >> 4;
    const int l3   = l15 & 3;

    __shared__ alignas(16) short As[128 * 32];
    __shared__ alignas(16) short Bs[128 * 32];

    floatx4 acc[4][4] = {};
    const int wm = (wave >> 1) * 64;
    const int wn = (wave & 1) * 64;

    // staging: 16 rows per issue (4 lanes/row), 2 issues/wave per buffer
    const int srl = lane >> 2;               // row within issue group (0..15)
    const int scc = (lane & 3) ^ (srl & 3);  // swizzled source chunk

    for (int k0 = 0; k0 < K; k0 += 32) {
        __syncthreads();
        #pragma unroll
        for (int j = 0; j < 2; ++j) {
            const int rs = 32 * wave + 16 * j;     // wave-uniform row start
            async_copy16(&A [(size_t)(bm + rs + srl) * K + k0 + 8 * scc], &As[rs * 32]);
            async_copy16(&BT[(size_t)(bn + rs + srl) * K + k0 + 8 * scc], &Bs[rs * 32]);
        }
        __syncthreads();

        bf16x8 af[4], bfr[4];
        #pragma unroll
        for (int mt = 0; mt < 4; ++mt)
            af[mt] = *reinterpret_cast<const bf16x8*>(&As[(wm + 16 * mt + l15) * 32 + 8 * (quad ^ l3)]);
        #pragma unroll
        for (int nt = 0; nt < 4; ++nt)
            bfr[nt] = *reinterpret_cast<const bf16x8*>(&Bs[(wn + 16 * nt + l15) * 32 + 8 * (quad ^ l3)]);
        #pragma unroll
        for (int mt = 0; mt < 4; ++mt)
            #pragma unroll
            for (int nt = 0; nt < 4; ++nt)
                acc[mt][nt] = __builtin_amdgcn_mfma_f32_16x16x32_bf16(af[mt], bfr[nt], acc[mt][nt], 0, 0, 0);
    }

    #pragma unroll
    for (int mt = 0; mt < 4; ++mt) {
        #pragma unroll
        for (int nt = 0; nt < 4; ++nt) {
            #pragma unroll
            for (int r = 0; r < 4; ++r) {
                const int row = bm + wm + mt * 16 + 4 * quad + r;
                const int col = bn + wn + nt * 16 + l15;
                float v = acc[mt][nt][r];
                if (MODE == 0) {
                    Cout[(size_t)row * N + col] = v + bias[col];
                } else {
                    const int proj   = col / kD;       // blocks never span projections
                    const int within = col - proj * kD;
                    const int h = within >> 6;
                    const int d = within & 63;
                    if (proj == 0)      Qh[((size_t)h * kN + row) * kHD + d] = f2b(v * kQScale);
                    else if (proj == 1) Kh[((size_t)h * kN + row) * kHD + d] = f2b(v);
                    else                Vt[((size_t)h * kHD + d) * kN + row] = f2b(v);
                }
            }
        }
    }
}

__global__ __launch_bounds__(256)
void gemm_qkv(const short* __restrict__ A, const short* __restrict__ BT,
              short* __restrict__ Qh, short* __restrict__ Kh, short* __restrict__ Vt)
{
    gemm_core<1>(A, BT, nullptr, nullptr, Qh, Kh, Vt, k3D, kD);
}

__global__ __launch_bounds__(256)
void gemm_out(const short* __restrict__ A, const short* __restrict__ BT,
              const float* __restrict__ bias, float* __restrict__ Cout)
{
    gemm_core<0>(A, BT, bias, Cout, nullptr, nullptr, nullptr, kD, kD);
}

// Flash attention v6: cross-tile software pipeline.
// Evidence r0-r4: no pipe >52% busy, wall per barrier-window ~3.5K cyc vs ~2K
// of work -> dependency-chain + barrier-lockstep bound (all waves burst the
// same pipe simultaneously, QK->exp->PV is serial within each window).
// v6 keeps v5's verified pieces (2x2 wave split: wave (wm,wk) owns 32 Q-rows x
// 32-of-64 kv; in-register P via cvt_pk + permlane; ones-MFMA denominator;
// XCD remap; dbuf KV=64) and reorders the loop so each window has independent
// MFMA and VALU work:
//   iter u: PV(u-1)            [MFMA: pa_prev + V(u-1) from old buffer]
//           barrier; stage(u+1) [into old buffer - PV reads already drained]
//           QK(u)              [MFMA from current buffer]
//           exp/pack(u)->pa     [VALU chain, overlaps next window's PV issue]
// Buffer invariant at iter u entry: buf[cur]=tile u, buf[cur^1]=tile u-1.
// Loop unrolled x2 with named paA/paB (no runtime-indexed fragments).
// Staging uses hoisted per-lane base pointers (addr math out of the loop).
// LDS = Ks 2x4K + Vs 2x4K shorts = 32KB; no min-occupancy bound.
__global__ __launch_bounds__(256)
void attn(const short* __restrict__ Qh, const short* __restrict__ Kh,
          const short* __restrict__ Vt, short* __restrict__ AO)
{
    const int flat = blockIdx.y * 64 + blockIdx.x;    // 0..767
    const int W    = (flat & 7) * 96 + (flat >> 3);   // bijective XCD remap
    const int h    = W >> 6;                          // W / 64
    const int q0   = (W & 63) * 64;

    const int tid  = threadIdx.x;
    const int wave = tid >> 6;          // 0..3
    const int lane = tid & 63;
    const int l15  = lane & 15;
    const int quad = lane >> 4;
    const int lx   = l15 & 7;
    const int wm   = wave >> 1;         // Q-row half owner
    const int wk   = wave & 1;          // KV half owner

    __shared__ alignas(16) short smem[16384];   // Ks[2]:0..8191, Vs[2]:8192..16383
    __shared__ float Dr[2][2][16];              // [wm][mt][4*quad+r] denom partials
    short* Ks0 = smem;
    short* Vs0 = smem + 8192;

    // Q fragments: B-operand of QK^T. qf[mt][s] = Q[q0+32wm+16mt+l15][32s+8quad..)
    bf16x8 qf[2][2];
    {
        const size_t qb = ((size_t)h * kN + q0 + 32 * wm + l15) * kHD;
        #pragma unroll
        for (int mt = 0; mt < 2; ++mt)
            #pragma unroll
            for (int s = 0; s < 2; ++s)
                qf[mt][s] = *reinterpret_cast<const bf16x8*>(
                    &Qh[qb + (size_t)(16 * mt) * kHD + 32 * s + 8 * quad]);
    }

    // all-ones B fragment: mfma(pa, ones) sums each P row -> softmax denom;
    // C-layout puts denom[row=16mt+4quad+r] in reg r of every lane.
    bf16x8 onesf;
    #pragma unroll
    for (int i = 0; i < 8; ++i) onesf[i] = (short)0x3F80;

    floatx4 oacc[2][4] = {};   // [mt][dt]: rows 32wm+16mt+4quad+r, cols 16dt+l15
    floatx4 dacc[2] = {};      // [mt] denom partial (this wave's kv half)

    // staging lane constants: each issue = 8 rows x 128B; physical chunk
    // (lane&7) holds logical chunk (lane&7)^(row&7)  (XOR swizzle)
    const int srl = lane >> 3;              // row within 8-row issue
    const int scc = (lane & 7) ^ srl;       // swizzled source chunk

    // hoisted per-lane staging base pointers (row 16*wave + srl, chunk scc)
    const short* kgp = &Kh[(size_t)h * kN * kHD +
                           (size_t)(16 * wave + srl) * kHD + 8 * scc];
    const short* vgp = &Vt[(size_t)h * kHD * kN +
                           (size_t)(16 * wave + srl) * kN + 8 * scc];
    short* kls = Ks0 + (16 * wave) * 64;    // wave's LDS dst base (K)
    short* vls = Vs0 + (16 * wave) * 64;    // wave's LDS dst base (V)

    auto stage = [&](int b, int kv0) {
        #pragma unroll
        for (int j = 0; j < 2; ++j) {
            async_copy16(kgp + (size_t)(kv0 + 8 * j) * kHD, kls + b * 4096 + (8 * j) * 64);
            async_copy16(vgp + (size_t)(8 * j) * kN + kv0,  vls + b * 4096 + (8 * j) * 64);
        }
    };

    // QK for tile in Kc, then exp/pack into pa (in-register A-fragment).
    auto qk_exp = [&](const short* Kc, bf16x8 (&pa)[2]) {
        floatx4 sacc[2][2] = {};   // [mt][nt]
        __builtin_amdgcn_s_setprio(1);
        #pragma unroll
        for (int nt = 0; nt < 2; ++nt) {
            #pragma unroll
            for (int s = 0; s < 2; ++s) {
                bf16x8 kf = *reinterpret_cast<const bf16x8*>(
                    &Kc[(32 * wk + 16 * nt + l15) * 64 + 8 * ((4 * s + quad) ^ lx)]);
                #pragma unroll
                for (int mt = 0; mt < 2; ++mt)
                    sacc[mt][nt] = __builtin_amdgcn_mfma_f32_16x16x32_bf16(
                        kf, qf[mt][s], sacc[mt][nt], 0, 0, 0);
            }
        }
        __builtin_amdgcn_s_setprio(0);
        // producer lane(l15,q') holds P[m][kv=16nt+4q'+r]; A-frag word algebra:
        // w0=[X0 X2 Y0 Y2], w2=[X1 X3 Y1 Y3] over quads = swap16(swap32(X,Y)).
        #pragma unroll
        for (int mt = 0; mt < 2; ++mt) {
            float e[2][4];
            #pragma unroll
            for (int nt = 0; nt < 2; ++nt)
                #pragma unroll
                for (int r = 0; r < 4; ++r)
                    e[nt][r] = fast_exp2(sacc[mt][nt][r]);
            unsigned x0 = cvt_pk_bf16(e[0][0], e[0][1]);
            unsigned y0 = cvt_pk_bf16(e[1][0], e[1][1]);
            unsigned x1 = cvt_pk_bf16(e[0][2], e[0][3]);
            unsigned y1 = cvt_pk_bf16(e[1][2], e[1][3]);
            permlane32_swap(x0, y0);
            permlane16_swap(x0, y0);
            permlane32_swap(x1, y1);
            permlane16_swap(x1, y1);
            union { uint4v u; bf16x8 v; } pu;
            pu.u[0] = x0; pu.u[1] = x1; pu.u[2] = y0; pu.u[3] = y1;
            pa[mt] = pu.v;
        }
    };

    // PV + denom for the tile whose V lives in Vc, P in pa.
    auto pv = [&](const short* Vc, const bf16x8 (&pa)[2]) {
        __builtin_amdgcn_s_setprio(1);
        #pragma unroll
        for (int dt = 0; dt < 4; ++dt) {
            bf16x8 vv = *reinterpret_cast<const bf16x8*>(
                &Vc[(16 * dt + l15) * 64 + 8 * ((4 * wk + quad) ^ lx)]);
            #pragma unroll
            for (int mt = 0; mt < 2; ++mt)
                oacc[mt][dt] = __builtin_amdgcn_mfma_f32_16x16x32_bf16(
                    pa[mt], vv, oacc[mt][dt], 0, 0, 0);
        }
        #pragma unroll
        for (int mt = 0; mt < 2; ++mt)
            dacc[mt] = __builtin_amdgcn_mfma_f32_16x16x32_bf16(
                pa[mt], onesf, dacc[mt], 0, 0, 0);
        __builtin_amdgcn_s_setprio(0);
    };

    constexpr int kNT = kN / 64;   // 64 tiles
    bf16x8 paA[2], paB[2];

    // tile 0 (no PV yet)
    stage(0, 0);
    __syncthreads();               // stage(0) drained
    stage(1, 64);
    qk_exp(Ks0, paA);
    int cur = 1;

    // tiles 1..62 in pairs (31 pairs); invariant at entry: buf[cur]=tile u,
    // buf[cur^1]=tile u-1, pa holds P(u-1).
    for (int tp = 0; tp < 31; ++tp) {
        const int u = 2 * tp + 1;
        // --- tile u ---
        pv(Vs0 + (cur ^ 1) * 4096, paA);
        __syncthreads();           // PV reads done everywhere; stage(u) drained
        stage(cur ^ 1, (u + 1) * 64);
        qk_exp(Ks0 + cur * 4096, paB);
        cur ^= 1;
        // --- tile u+1 ---
        pv(Vs0 + (cur ^ 1) * 4096, paB);
        __syncthreads();
        stage(cur ^ 1, (u + 2) * 64);
        qk_exp(Ks0 + cur * 4096, paA);
        cur ^= 1;
    }

    // tile 63
    pv(Vs0 + (cur ^ 1) * 4096, paA);
    __syncthreads();               // stage(63) drained
    qk_exp(Ks0 + cur * 4096, paB);
    pv(Vs0 + cur * 4096, paB);     // final PV (no further staging)

    // ---- epilogue: combine wk=0/1 partials (O and denom) ----
    __syncthreads();   // all main-loop LDS reads done; smem reusable
    float* red = reinterpret_cast<float*>(smem);   // 4096 floats = 16KB
    if (wk == 1) {
        #pragma unroll
        for (int mt = 0; mt < 2; ++mt)
            #pragma unroll
            for (int dt = 0; dt < 4; ++dt)
                *reinterpret_cast<floatx4*>(
                    &red[wm * 2048 + (mt * 4 + dt) * 256 + l15 * 16 + quad * 4]) =
                    oacc[mt][dt];
        if (l15 == 0) {
            #pragma unroll
            for (int mt = 0; mt < 2; ++mt)
                #pragma unroll
                for (int r = 0; r < 4; ++r)
                    Dr[wm][mt][4 * quad + r] = dacc[mt][r];
        }
    }
    __syncthreads();
    if (wk == 0) {
        #pragma unroll
        for (int mt = 0; mt < 2; ++mt) {
            #pragma unroll
            for (int dt = 0; dt < 4; ++dt)
                oacc[mt][dt] += *reinterpret_cast<const floatx4*>(
                    &red[wm * 2048 + (mt * 4 + dt) * 256 + l15 * 16 + quad * 4]);
            float inv[4];
            #pragma unroll
            for (int r = 0; r < 4; ++r)
                inv[r] = 1.0f / (dacc[mt][r] + Dr[wm][mt][4 * quad + r]);
            #pragma unroll
            for (int dt = 0; dt < 4; ++dt) {
                #pragma unroll
                for (int r = 0; r < 4; ++r) {
                    const int row = q0 + 32 * wm + 16 * mt + 4 * quad + r;
                    const int col = h * kHD + 16 * dt + l15;
                    AO[(size_t)row * kD + col] = f2b(oacc[mt][dt][r] * inv[r]);
                }
            }
        }
    }
}

extern "C" void kernel_launch(void* const* d_in, const int* in_sizes, int n_in,
                              void* d_out, int out_size, void* d_ws, size_t ws_size,
                              hipStream_t stream)
{
    const float* x     = (const float*)d_in[0];  // (4096, 768) fp32
    const float* W_qkv = (const float*)d_in[1];  // (768, 2304) fp32
    const float* W_out = (const float*)d_in[2];  // (768, 768)  fp32
    const float* b_out = (const float*)d_in[3];  // (768,)      fp32
    float* out = (float*)d_out;                  // (4096, 768) fp32

    const size_t HNHD = (size_t)kH * kN * kHD;   // 3,145,728 shorts per tensor
    short* Qh    = (short*)d_ws;                 // [H][N][64]
    short* Kh    = Qh + HNHD;
    short* Vt    = Kh + HNHD;                    // [H][64][N]
    short* Xb    = Vt + HNHD;                    // x bf16 [N][768]; reused as AO
    short* WqkvT = Xb + (size_t)kN * kD;         // [2304][768]
    short* WoutT = WqkvT + (size_t)k3D * kD;     // [768][768]
    short* AO    = Xb;                           // overlay: Xb dead after QKV gemm
    (void)in_sizes; (void)n_in; (void)out_size; (void)ws_size;

    // 0) fused conversions/transposes (one launch)
    prep<<<dim3(kBlkX + kBlkWq + kBlkWo), dim3(256), 0, stream>>>(
        x, W_qkv, W_out, Xb, WqkvT, WoutT);

    // 1) QKV projection + head scatter (Q pre-scaled, V transposed)
    gemm_qkv<<<dim3(kN / 128, k3D / 128), dim3(256), 0, stream>>>(
        Xb, WqkvT, Qh, Kh, Vt);
    // 2) flash attention (2x2 wave split, cross-tile software pipeline)
    attn<<<dim3(kN / 64, kH), dim3(256), 0, stream>>>(Qh, Kh, Vt, AO);
    // 3) output projection + bias -> fp32
    gemm_out<<<dim3(kN / 128, kD / 128), dim3(256), 0, stream>>>(
        AO, WoutT, b_out, out);
}